// Round 11
// baseline (1163.024 us; speedup 1.0000x reference)
//
#include <hip/hip_runtime.h>
#include <stdint.h>

typedef float f32x4 __attribute__((ext_vector_type(4)));

// Pure-f32 fused MLP, 64 rows/block, 256 threads, 4 waves, 4 blocks/CU.
// r11 = r4 structure, but ALL weights (W1/W2/W3) read directly from global
// (L2-resident, wave-coalesced 64B/instr) -> LDS pipe carries only A/h1/h2.
// Per-kt: 4 LDS reads + 8 VMEM + 128 FMA => VALU-bound. Bit-identical to r4.
__global__ __launch_bounds__(256, 4) void mlp_kernel(
    const float* __restrict__ data,
    const float* __restrict__ W1, const float* __restrict__ b1,
    const float* __restrict__ W2, const float* __restrict__ b2,
    const float* __restrict__ W3, const float* __restrict__ b3,
    const float* __restrict__ Wout, const float* __restrict__ bout,
    float* __restrict__ proj)
{
    __shared__ __align__(16) char smem[33792];
    float* a_s = (float*)(smem);           // L1: A tile [64][32] swz, 8 KB
    float* h1s = (float*)(smem);           // L2: [64][132], 33792 B (a_s dead)
    float* h2s = (float*)(smem);           // L3: [64][68], 17408 B (h1s dead)

    const int tid = threadIdx.x;
    const size_t row0 = (size_t)blockIdx.x * 64;
    const int ty = tid & 15, tx = tid >> 4;    // L1 compute map (r4)
    const int sr = tid >> 2, q  = tid & 3;     // A-stage map (r4)

    // ---------------- Layer 1: 24 full k-tiles of 32 + 16-k tail ----------------
    float acc[4][8] = {};

    #pragma unroll 1
    for (int it = 0; it < 24; ++it) {
        const int kb = it * 32;
        // stage A tile -> a_s [64][32], r4 swizzle (no guards needed, k<768+32<=784)
        #pragma unroll
        for (int j = 0; j < 2; ++j) {
            const int kg = q + 4*j;
            f32x4 v = *(const f32x4*)(data + (row0 + sr)*784 + kb + kg*4);
            *(f32x4*)(a_s + sr*32 + ((kg ^ ((sr >> 2) & 7)) << 2)) = v;
        }
        __syncthreads();
        #pragma unroll
        for (int kt = 0; kt < 8; ++kt) {
            f32x4 av[4];
            #pragma unroll
            for (int r = 0; r < 4; ++r)
                av[r] = *(const f32x4*)(a_s + (ty*4 + r)*32 + ((kt ^ (ty & 7)) << 2));
            #pragma unroll
            for (int kk = 0; kk < 4; ++kk) {
                const float* wp = W1 + (size_t)(kb + kt*4 + kk)*128 + tx*8;
                f32x4 w0  = *(const f32x4*)(wp);
                f32x4 w1v = *(const f32x4*)(wp + 4);
                #pragma unroll
                for (int r = 0; r < 4; ++r) {
                    const float a = av[r][kk];
                    #pragma unroll
                    for (int c = 0; c < 4; ++c) {
                        acc[r][c]     += a * w0[c];
                        acc[r][4 + c] += a * w1v[c];
                    }
                }
            }
        }
        __syncthreads();
    }
    // tail: k = 768..783 (kt 0..3 only; W reads stay in-bounds)
    {
        #pragma unroll
        for (int j = 0; j < 2; ++j) {
            const int kg = q + 4*j;
            const int col = 768 + kg*4;
            f32x4 v = {};
            if (col < 784) v = *(const f32x4*)(data + (row0 + sr)*784 + col);
            *(f32x4*)(a_s + sr*32 + ((kg ^ ((sr >> 2) & 7)) << 2)) = v;
        }
        __syncthreads();
        #pragma unroll
        for (int kt = 0; kt < 4; ++kt) {
            f32x4 av[4];
            #pragma unroll
            for (int r = 0; r < 4; ++r)
                av[r] = *(const f32x4*)(a_s + (ty*4 + r)*32 + ((kt ^ (ty & 7)) << 2));
            #pragma unroll
            for (int kk = 0; kk < 4; ++kk) {
                const float* wp = W1 + (size_t)(768 + kt*4 + kk)*128 + tx*8;
                f32x4 w0  = *(const f32x4*)(wp);
                f32x4 w1v = *(const f32x4*)(wp + 4);
                #pragma unroll
                for (int r = 0; r < 4; ++r) {
                    const float a = av[r][kk];
                    #pragma unroll
                    for (int c = 0; c < 4; ++c) {
                        acc[r][c]     += a * w0[c];
                        acc[r][4 + c] += a * w1v[c];
                    }
                }
            }
        }
        __syncthreads();   // a_s dead; safe to overwrite as h1s
    }

    // L1 epilogue: bias + relu -> h1s [64][132] (r4 verbatim)
    #pragma unroll
    for (int r = 0; r < 4; ++r) {
        const int m = ty*4 + r;
        #pragma unroll
        for (int c = 0; c < 8; ++c) {
            const int col = tx*8 + c;
            float v = acc[r][c] + b1[col];
            h1s[m*132 + col] = v > 0.f ? v : 0.f;
        }
    }
    __syncthreads();

    // ---------------- Layer 2: W2 direct from global, NO barriers ----------------
    const int m2 = tid >> 2, nq = tid & 3;
    float h2a[16];
    #pragma unroll
    for (int i = 0; i < 16; ++i) h2a[i] = b2[nq*16 + i];
    #pragma unroll 1
    for (int p = 0; p < 8; ++p) {
        #pragma unroll
        for (int qq = 0; qq < 4; ++qq) {
            f32x4 hq = *(const f32x4*)(h1s + m2*132 + p*16 + qq*4);
            #pragma unroll
            for (int kk = 0; kk < 4; ++kk) {
                #pragma unroll
                for (int i = 0; i < 4; ++i) {
                    f32x4 wv2 = *(const f32x4*)(W2 + (size_t)(p*16 + qq*4 + kk)*64 + nq*16 + i*4);
                    #pragma unroll
                    for (int c = 0; c < 4; ++c) h2a[i*4 + c] += hq[kk] * wv2[c];
                }
            }
        }
    }
    __syncthreads();   // all h1s reads done; safe to overwrite as h2s
    #pragma unroll
    for (int i = 0; i < 4; ++i) {
        f32x4 v;
        #pragma unroll
        for (int c = 0; c < 4; ++c) { float x = h2a[i*4 + c]; v[c] = x > 0.f ? x : 0.f; }
        *(f32x4*)(h2s + m2*68 + nq*16 + i*4) = v;
    }
    __syncthreads();

    // ---------------- Layer 3: W3 direct from global (r4 order) ----------------
    const int m3 = tid >> 2, nq3 = tid & 3;
    float h3a[8];
    #pragma unroll
    for (int i = 0; i < 8; ++i) h3a[i] = b3[nq3*8 + i];
    #pragma unroll 1
    for (int qq = 0; qq < 16; ++qq) {
        f32x4 hq = *(const f32x4*)(h2s + m3*68 + qq*4);
        #pragma unroll
        for (int kk = 0; kk < 4; ++kk) {
            #pragma unroll
            for (int i2 = 0; i2 < 2; ++i2) {
                f32x4 wv3 = *(const f32x4*)(W3 + (size_t)(qq*4 + kk)*32 + nq3*8 + i2*4);
                #pragma unroll
                for (int c = 0; c < 4; ++c) h3a[i2*4 + c] += hq[kk] * wv3[c];
            }
        }
    }
    // ---------------- Layer 4: relu + Wout, 4-lane shuffle reduce (r4) ----------------
    float p0 = 0.f, p1 = 0.f;
    #pragma unroll
    for (int i = 0; i < 8; ++i) {
        const int k = nq3*8 + i;
        float h = h3a[i] > 0.f ? h3a[i] : 0.f;
        p0 += h * Wout[k*2 + 0];
        p1 += h * Wout[k*2 + 1];
    }
    p0 += __shfl_xor(p0, 1); p0 += __shfl_xor(p0, 2);
    p1 += __shfl_xor(p1, 1); p1 += __shfl_xor(p1, 2);
    if (nq3 == 0) {
        proj[(row0 + m3)*2 + 0] = p0 + bout[0];
        proj[(row0 + m3)*2 + 1] = p1 + bout[1];
    }
}

// gather + squared distance, f32 out (r4 verbatim)
__global__ __launch_bounds__(256) void dist_kernel(
    const float* __restrict__ proj, const int* __restrict__ idxs,
    float* __restrict__ out, int total)
{
    int gid = blockIdx.x * 256 + threadIdx.x;
    if (gid >= total) return;
    unsigned i = (unsigned)gid / 10u;
    unsigned j = (unsigned)idxs[gid];
    float dx = proj[i*2 + 0] - proj[j*2 + 0];
    float dy = proj[i*2 + 1] - proj[j*2 + 1];
    out[gid] = dx*dx + dy*dy;
}

extern "C" void kernel_launch(void* const* d_in, const int* in_sizes, int n_in,
                              void* d_out, int out_size, void* d_ws, size_t ws_size,
                              hipStream_t stream)
{
    const float* data = (const float*)d_in[0];
    const int*   idxs = (const int*)d_in[1];
    const float* W1   = (const float*)d_in[2];
    const float* b1   = (const float*)d_in[3];
    const float* W2   = (const float*)d_in[4];
    const float* b2   = (const float*)d_in[5];
    const float* W3   = (const float*)d_in[6];
    const float* b3   = (const float*)d_in[7];
    const float* Wout = (const float*)d_in[8];
    const float* bout = (const float*)d_in[9];

    const int N = in_sizes[0] / 784;           // 200000, divisible by 64
    float* proj = (float*)d_ws;                // N*2 f32 = 1,600,000 B

    mlp_kernel<<<N / 64, 256, 0, stream>>>(data, W1, b1, W2, b2, W3, b3, Wout, bout, proj);
    dist_kernel<<<(N*10 + 255) / 256, 256, 0, stream>>>(proj, idxs, (float*)d_out, N*10);
}